// Round 10
// baseline (52.033 us; speedup 1.0000x reference)
//
#include <hip/hip_runtime.h>
#include <math.h>

// FactorMuE: profile-HMM forward log-likelihood.
// Dims (static): M=128, Mp1=129, K=258, D=21, ZD=64, B=64, L=256, P=774.
// Reference-fidelity detail: row k=128 of the transition matrix is all
// NEG=-1e32; the reference's float32 row-lse absorbs log(258), so the
// normalized row is 0.0 -> linear outflow weight 1.0 PER DESTINATION.
#define MP1 129
#define KK  258
#define DD  21
#define ZDIM 64
#define BB  64
#define LL  256

// ---------------- ws layout (floats) ----------------
// ETg: [64][22][64][4] transposed emission table = 360448
// E2g: [64][22][2]                               = 2816
// tok: [64][256] int32                           = 16384
#define OFF_ETG  0
#define OFF_E2G  360448
#define OFF_TOK  363264
#define OFF_COEF 379648
#define C_UU   0
#define C_DXM  258
#define C_DXI  516
#define C_WM   774
#define C_WI   903
#define C_DMID 1032
#define C_PI0  1160

#define EMIS_BLKS 65     // 260 waves >= 258 (c,m)-rows, one wave per row
#define TOK_BLKS  1366   // 5464 waves, 3 rows each, single iteration

// -------- DPP helpers (cross-lane on the VALU pipe) --------
template <int CTRL, int RM, int BM>
__device__ __forceinline__ float updpp(float old, float src) {
    return __int_as_float(__builtin_amdgcn_update_dpp(
        __float_as_int(old), __float_as_int(src), CTRL, RM, BM, false));
}
// single-instruction shift with bound_ctrl=1 (shifted-in lanes read 0)
template <int CTRL>
__device__ __forceinline__ float movdpp0(float src) {
#if __has_builtin(__builtin_amdgcn_mov_dpp)
    return __int_as_float(__builtin_amdgcn_mov_dpp(
        __float_as_int(src), CTRL, 0xf, 0xf, true));
#else
    return __int_as_float(__builtin_amdgcn_update_dpp(
        0, __float_as_int(src), CTRL, 0xf, 0xf, true));
#endif
}
__device__ __forceinline__ float readlane_f(float v, int lane) {
    return __int_as_float(__builtin_amdgcn_readlane(__float_as_int(v), lane));
}
__device__ __forceinline__ float wave_sum_to63(float s) {
    s += movdpp0<0x111>(s);                // row_shr:1
    s += movdpp0<0x112>(s);                // row_shr:2
    s += movdpp0<0x114>(s);                // row_shr:4
    s += movdpp0<0x118>(s);                // row_shr:8
    s += updpp<0x142, 0xa, 0xf>(0.f, s);   // row_bcast:15 -> rows 1,3
    s += updpp<0x143, 0xc, 0xf>(0.f, s);   // row_bcast:31 -> rows 2,3
    return s;
}

// ==================== fused setup: coef | emis | tok by block role ====================
__global__ __launch_bounds__(256, 1) void k_setup(const float* __restrict__ z,
                                                  const float* __restrict__ W,
                                                  const float* __restrict__ bias,
                                                  const float* __restrict__ invt,
                                                  const float* __restrict__ data,
                                                  const float* __restrict__ ins,
                                                  const float* __restrict__ del,
                                                  float* __restrict__ ETg,
                                                  float* __restrict__ E2g,
                                                  int* __restrict__ tokout,
                                                  float* __restrict__ coef) {
    __shared__ float il[774], dl[774], Smid[129], Qs[130];
    int bid = blockIdx.x;
    int tid = threadIdx.x;

    if (bid >= 1 && bid <= EMIS_BLKS) {
        // ---- emission: wave = one (c,m)-row rr, lane = batch b ----
        int b  = tid & 63;
        int rr = __builtin_amdgcn_readfirstlane((bid - 1) * 4 + (tid >> 6));
        if (rr >= KK) return;
        float it = log1pf(expf(invt[0]));          // softplus
        const float* wb = W + (size_t)rr * DD * ZDIM;   // wave-uniform
        const float* bp = bias + rr * DD;
        float acc[DD];
        #pragma unroll
        for (int d = 0; d < DD; ++d) acc[d] = bp[d];
        const float4* zp = (const float4*)(z + (size_t)b * ZDIM);
        #pragma unroll
        for (int c = 0; c < 4; ++c) {              // 4 chunks x 16 floats (no spill)
            float4 za = zp[4 * c + 0], zb = zp[4 * c + 1];
            float4 zc = zp[4 * c + 2], zd = zp[4 * c + 3];
            #pragma unroll
            for (int d = 0; d < DD; ++d) {
                const float4* wp = (const float4*)(wb + (size_t)d * ZDIM + 16 * c);
                float4 wa = wp[0], wv = wp[1], wc = wp[2], wd = wp[3];
                float a = acc[d];
                a = fmaf(za.x, wa.x, a); a = fmaf(za.y, wa.y, a);
                a = fmaf(za.z, wa.z, a); a = fmaf(za.w, wa.w, a);
                a = fmaf(zb.x, wv.x, a); a = fmaf(zb.y, wv.y, a);
                a = fmaf(zb.z, wv.z, a); a = fmaf(zb.w, wv.w, a);
                a = fmaf(zc.x, wc.x, a); a = fmaf(zc.y, wc.y, a);
                a = fmaf(zc.z, wc.z, a); a = fmaf(zc.w, wc.w, a);
                a = fmaf(zd.x, wd.x, a); a = fmaf(zd.y, wd.y, a);
                a = fmaf(zd.z, wd.z, a); a = fmaf(zd.w, wd.w, a);
                acc[d] = a;
            }
        }
        float mx = acc[0] * it;
        #pragma unroll
        for (int d = 0; d < DD; ++d) { acc[d] *= it; mx = fmaxf(mx, acc[d]); }
        float s = 0.f;
        #pragma unroll
        for (int d = 0; d < DD; ++d) { acc[d] = expf(acc[d] - mx); s += acc[d]; }
        float inv = 1.0f / s;
        // write TRANSPOSED layout consumed by k_fwd without repack:
        //   match m<128 : ETg[b][d][m>>1][m&1]
        //   insert m<128: ETg[b][d][m>>1][2+(m&1)]
        //   match 128 / insert 128 -> E2g[b][d][0/1]
        if (rr == 128 || rr == 257) {
            float* eb = E2g + b * 44 + ((rr == 128) ? 0 : 1);
            #pragma unroll
            for (int d = 0; d < DD; ++d) eb[d * 2] = acc[d] * inv;
            eb[DD * 2] = 1.0f;                     // ones row (missing token)
        } else {
            bool ism = rr < 128;
            int m = ism ? rr : rr - MP1;
            int slot = (m >> 1) * 4 + (ism ? 0 : 2) + (m & 1);
            float* eb = ETg + (size_t)b * 5632 + slot;
            #pragma unroll
            for (int d = 0; d < DD; ++d) eb[d * 256] = acc[d] * inv;
            eb[DD * 256] = 1.0f;                   // ones row (missing token)
        }
        return;
    }
    if (bid > EMIS_BLKS) {
        // ---- token extraction via ballot: 3 rows per wave, one iteration ----
        int wid  = (bid - 1 - EMIS_BLKS) * 4 + (tid >> 6);
        int lane = tid & 63;
        int r3   = lane / 21;                            // 0..3 (lane 63 idle)
        int d    = lane - r3 * 21;
        int row  = wid * 3 + r3;
        float v = 0.f;
        if (r3 < 3 && row < BB * LL) v = data[(size_t)row * DD + d];
        unsigned long long m = __ballot(v > 0.5f);
        if (r3 < 3 && d == 0 && row < BB * LL) {
            unsigned long long slice = (m >> (21 * r3)) & 0x1FFFFFULL;
            tokout[row] = slice ? (int)__builtin_ctzll(slice) : DD;
        }
        return;
    }
    // ---- bid 0: transition coefficients (O(1) per row via suffix-LSE) ----
    int t = tid;
    for (int p = t; p < 387; p += 256) {
        float x0 = ins[2 * p], x1 = ins[2 * p + 1];
        float mx = fmaxf(x0, x1);
        float ls = mx + logf(expf(x0 - mx) + expf(x1 - mx));
        il[2 * p] = x0 - ls; il[2 * p + 1] = x1 - ls;
        float y0 = del[2 * p], y1 = del[2 * p + 1];
        float my = fmaxf(y0, y1);
        float lt = my + logf(expf(y0 - my) + expf(y1 - my));
        dl[2 * p] = y0 - lt; dl[2 * p + 1] = y1 - lt;
    }
    __syncthreads();
    if (t < 64) {   // Smid prefix sum, wave 0
        int mmA = 1 + 2 * t, mmB = 2 + 2 * t;
        float xA = il[(mmA * 3 + 2) * 2 + 0] + dl[(mmA * 3 + 2) * 2 + 1];
        float xB = il[(mmB * 3 + 2) * 2 + 0] + dl[(mmB * 3 + 2) * 2 + 1];
        float sc = xA + xB;
        #pragma unroll
        for (int off = 1; off < 64; off <<= 1) {
            float vv = __shfl_up(sc, off);
            if (t >= off) sc += vv;
        }
        Smid[mmB] = sc;
        Smid[mmA] = sc - xB;
        if (t == 0) Smid[0] = 0.f;
    }
    __syncthreads();
    if (t < 64) {
        // suffix-LSE over P[mp] = Smid[mp-1] + LSE(ilM+dlM, ilI), mp=1..128.
        int mpA = 128 - 2 * t, mpB = 127 - 2 * t;
        float aM_ = il[(mpA * 3 + 2) * 2 + 0] + dl[(mpA * 3 + 2) * 2 + 0];
        float aI_ = il[(mpA * 3 + 2) * 2 + 1];
        float mA = fmaxf(aM_, aI_);
        float pA = Smid[mpA - 1] + mA + logf(expf(aM_ - mA) + expf(aI_ - mA));
        float bM_ = il[(mpB * 3 + 2) * 2 + 0] + dl[(mpB * 3 + 2) * 2 + 0];
        float bI_ = il[(mpB * 3 + 2) * 2 + 1];
        float mB = fmaxf(bM_, bI_);
        float pB = Smid[mpB - 1] + mB + logf(expf(bM_ - mB) + expf(bI_ - mB));
        float cm = fmaxf(pA, pB);
        float cs = expf(pA - cm) + expf(pB - cm);
        #pragma unroll
        for (int off = 1; off < 64; off <<= 1) {
            float om = __shfl_up(cm, off);
            float os = __shfl_up(cs, off);
            if (t >= off) {
                float M = fmaxf(cm, om);
                cs = cs * expf(cm - M) + os * expf(om - M);
                cm = M;
            }
        }
        Qs[mpB] = cm + logf(cs);
        float em = __shfl_up(cm, 1), es = __shfl_up(cs, 1);
        if (t == 0) Qs[128] = pA;
        else {
            float M = fmaxf(em, pA);
            Qs[mpA] = M + logf(es * expf(em - M) + expf(pA - M));
        }
        if (t == 0) Qs[129] = -1e30f;
    }
    __syncthreads();
    float* uu  = coef + C_UU;
    float* dxM = coef + C_DXM;
    float* dxI = coef + C_DXI;
    float* wM  = coef + C_WM;
    float* wI  = coef + C_WI;
    float* dmd = coef + C_DMID;
    float* pi0 = coef + C_PI0;
    for (int k = t; k < KK; k += 256) {
        if (k == 128) { uu[k] = 0.f; dxM[k] = 0.f; dxI[k] = 0.f; continue; }
        int g  = (k < MP1) ? 0 : 1;
        int n0 = g ? (k - MP1) : (k + 1);
        float i0 = il[(n0 * 3 + g) * 2 + 0], i1 = il[(n0 * 3 + g) * 2 + 1];
        float e0 = dl[(n0 * 3 + g) * 2 + 0], e1 = dl[(n0 * 3 + g) * 2 + 1];
        float diagM = i0 + e0;
        float diagI = i1;
        float src   = i0 + e1;
        float tail  = src - Smid[n0] + Qs[n0 + 1];
        float M3 = fmaxf(fmaxf(diagM, diagI), tail);
        float ssum = expf(diagM - M3) + expf(diagI - M3) + expf(tail - M3);
        float lse = M3 + logf(ssum);
        uu[k]  = expf(src - lse);
        dxM[k] = expf(diagM - lse);
        dxI[k] = expf(diagI - lse);
    }
    for (int mp = t; mp < MP1; mp += 256) {
        wM[mp] = expf(il[(mp * 3 + 2) * 2 + 0] + dl[(mp * 3 + 2) * 2 + 0]);
        wI[mp] = expf(il[(mp * 3 + 2) * 2 + 1]);
    }
    for (int tt = t; tt < 128; tt += 256)
        dmd[tt] = (tt == 0) ? 1.f : expf(il[(tt * 3 + 2) * 2 + 0] + dl[(tt * 3 + 2) * 2 + 1]);
    __syncthreads();
    {   // pi0: O(1) per state via Qs
        float i00 = il[0], i01 = il[1], d00 = dl[0], d01 = dl[1];
        float a00 = i00 + d00, a0129 = i01;
        float tail0 = i00 + d01 + Qs[1];
        float M3 = fmaxf(fmaxf(a00, a0129), tail0);
        float lse0 = M3 + logf(expf(a00 - M3) + expf(a0129 - M3) + expf(tail0 - M3));
        for (int kp = t; kp < KK; kp += 256) {
            int gp = (kp >= MP1);
            int mp = gp ? (kp - MP1) : kp;
            float v;
            if (mp == 0) v = gp ? a0129 : a00;
            else v = i00 + d01 + Smid[mp - 1] +
                     (gp ? il[(mp * 3 + 2) * 2 + 1]
                         : il[(mp * 3 + 2) * 2 + 0] + dl[(mp * 3 + 2) * 2 + 0]);
            pi0[kp] = expf(v - lse0);
        }
    }
}

// ==================== forward scan: 1 wave/batch, scalar minimal-instr steps ====================
__global__ __launch_bounds__(64) void k_fwd(const float* __restrict__ ETg,
                                            const float* __restrict__ E2g,
                                            const int* __restrict__ tokg,
                                            const float* __restrict__ coef,
                                            float* __restrict__ out) {
    const float* uu  = coef + C_UU;
    const float* dxM = coef + C_DXM;
    const float* dxI = coef + C_DXI;
    const float* wMg = coef + C_WM;
    const float* wIg = coef + C_WI;
    const float* dmd = coef + C_DMID;
    const float* pi0 = coef + C_PI0;
    __shared__ float ETLs[22 * 256];       // [tok][lane][4]
    int lane = threadIdx.x;
    int b = blockIdx.x;
    const float4* srcp = (const float4*)(ETg + (size_t)b * 5632);
    float4* dstp = (float4*)ETLs;
    for (int i = lane; i < 1408; i += 64) dstp[i] = srcp[i];
    float e2m = 0.f, e2i = 0.f;
    if (lane < 22) {
        e2m = E2g[b * 44 + lane * 2 + 0];
        e2i = E2g[b * 44 + lane * 2 + 1];
    }
    int4 tkv = ((const int4*)(tokg + b * LL))[lane];   // tokens 4*lane..4*lane+3
    __syncthreads();

    int m0 = 2 * lane, m1 = 2 * lane + 1;
    bool L0 = (lane == 0), L63 = (lane == 63);
    float f63 = L63 ? 1.f : 0.f;
    float cM0 = L0 ? 0.f : uu[m0 - 1];
    float cM1 = uu[m0];
    float cI0 = uu[129 + m0], cI1 = uu[129 + m1];
    float d0 = dmd[m0], d1v = dmd[m1];
    float Apair = d0 * d1v;
    float wM0 = wMg[m0], wM1 = wMg[m1], wI0 = wIg[m0], wI1 = wIg[m1];
    float xMA0 = L0 ? 0.f : dxM[m0 - 1], xIA0 = L0 ? 0.f : dxI[m0 - 1];
    float xMA1 = dxM[m0], xIA1 = dxI[m0];
    float xMB0 = dxM[129 + m0], xMB1 = dxM[129 + m1];
    float xIB0 = dxI[129 + m0], xIB1 = dxI[129 + m1];
    float wM2 = L63 ? wMg[128] : 0.f, wI2 = L63 ? wIg[128] : 0.f;
    float xMA2 = L63 ? dxM[127] : 0.f, xIA2 = L63 ? dxI[127] : 0.f;
    float xMB2 = L63 ? dxM[257] : 0.f, xIB2 = L63 ? dxI[257] : 0.f;

    // step-invariant Kogge-Stone A-levels (precompute once; update_dpp fine here)
    float A0 = Apair;
    float A1 = A0 * updpp<0x111, 0xf, 0xf>(1.f, A0);
    float A2 = A1 * updpp<0x112, 0xf, 0xf>(1.f, A1);
    float A3 = A2 * updpp<0x114, 0xf, 0xf>(1.f, A2);
    float A4 = A3 * updpp<0x118, 0xf, 0xf>(1.f, A3);
    float A5 = A4 * updpp<0x142, 0xa, 0xf>(1.f, A4);
    unsigned long long bbf = __ballot(Apair >= 1.0e-3f);
    int fast = (bbf == 0ULL);

    // init: alpha0 = pi0 * E(tok0)
    int lidx = lane * 4;
    int tok0 = __builtin_amdgcn_readlane(tkv.x, 0);
    float4 q0 = *(const float4*)(ETLs + tok0 * 256 + lidx);
    float aM0 = pi0[m0] * q0.x;
    float aM1 = pi0[m1] * q0.y;
    float aI0 = pi0[129 + m0] * q0.z;
    float aI1 = pi0[129 + m1] * q0.w;
    float aM2 = f63 * pi0[128] * readlane_f(e2m, tok0);
    float aI2 = f63 * pi0[257] * readlane_f(e2i, tok0);

    int etot = 0;
    float part = ((aM0 + aM1) + (aI0 + aI1)) + (aM2 + aI2);
    float vsum = wave_sum_to63(part);      // pending reduction (lagged rescale)

    // 4 rotating E buffers + token ids (refilled 4 steps ahead)
    float4 q1, q2, q3, q4;
    int st1, st2, st3, st4;
#define LOADR(QN, SN, TN)                                                    \
    { int tn_ = (TN); SN = tn_;                                              \
      QN = *(const float4*)(ETLs + tn_ * 256 + lidx); }
    LOADR(q1, st1, __builtin_amdgcn_readlane(tkv.y, 0));   // step 1
    LOADR(q2, st2, __builtin_amdgcn_readlane(tkv.z, 0));   // step 2
    LOADR(q3, st3, __builtin_amdgcn_readlane(tkv.w, 0));   // step 3
    LOADR(q4, st4, __builtin_amdgcn_readlane(tkv.x, 1));   // step 4

    // scalar step: EX* = E-fragment values (invs pre-folded on rescale steps),
    // EMM/EII = E2 values with f63 (and invs) pre-folded.
#define STEP_BODY(NL, EX0, EX1, EX2, EX3, EMM, EII, DOPART)                  \
    {                                                                        \
        float aMp  = movdpp0<0x138>(aM1);            /* wf_shr:1, lane0->0 */\
        float u128 = readlane_f(aM2, 63);                                    \
        float r0 = fmaf(aMp, cM0, aI0 * cI0);                                \
        float r1 = fmaf(aM0, cM1, aI1 * cI1);                                \
        float B = fmaf(d1v, r0, r1);                                         \
        B = fmaf(A0, movdpp0<0x111>(B), B);                                  \
        if (NL > 1) {                                                        \
            B = fmaf(A1, movdpp0<0x112>(B), B);                              \
            B = fmaf(A2, movdpp0<0x114>(B), B);                              \
            B = fmaf(A3, movdpp0<0x118>(B), B);                              \
            B = fmaf(A4, updpp<0x142, 0xa, 0xf>(0.f, B), B);                 \
            B = fmaf(A5, updpp<0x143, 0xc, 0xf>(0.f, B), B);                 \
        }                                                                    \
        float G0 = movdpp0<0x138>(B);                /* exclusive shift */   \
        float G1 = fmaf(d0, G0, r0);                                         \
        float mM0 = fmaf(wM0, G0, fmaf(xMA0, aMp, fmaf(xMB0, aI0, u128)));   \
        float mI0 = fmaf(wI0, G0, fmaf(xIA0, aMp, fmaf(xIB0, aI0, u128)));   \
        float mM1 = fmaf(wM1, G1, fmaf(xMA1, aM0, fmaf(xMB1, aI1, u128)));   \
        float mI1 = fmaf(wI1, G1, fmaf(xIA1, aM0, fmaf(xIB1, aI1, u128)));   \
        float mM2 = fmaf(wM2, B,  fmaf(xMA2, aM1, fmaf(xMB2, aI2, u128)));   \
        float mI2 = fmaf(wI2, B,  fmaf(xIA2, aM1, fmaf(xIB2, aI2, u128)));   \
        aM0 = mM0 * EX0;                                                     \
        aM1 = mM1 * EX1;                                                     \
        aI0 = mI0 * EX2;                                                     \
        aI1 = mI1 * EX3;                                                     \
        aM2 = mM2 * EMM;                             /* f63 folded in EMM */ \
        aI2 = mI2 * EII;                                                     \
        if (DOPART) part = ((aM0 + aM1) + (aI0 + aI1)) + (aM2 + aI2);        \
    }

#define GROUP(NL, IT)                                                        \
    {                                                                        \
        /* finalize lagged rescale from pending vsum */                      \
        float stot = readlane_f(vsum, 63);                                   \
        int sb = __float_as_int(stot) & 0x7f800000;                          \
        etot += (sb >> 23);                                                  \
        float invs = __int_as_float(0x7f000000 - sb);                        \
        float vinv63 = f63 * invs;                                           \
        float em1 = readlane_f(e2m, st1) * vinv63;                           \
        float ei1 = readlane_f(e2i, st1) * vinv63;                           \
        float em2 = readlane_f(e2m, st2) * f63;                              \
        float ei2 = readlane_f(e2i, st2) * f63;                              \
        float em3 = readlane_f(e2m, st3) * f63;                              \
        float ei3 = readlane_f(e2i, st3) * f63;                              \
        float em4 = readlane_f(e2m, st4) * f63;                              \
        float ei4 = readlane_f(e2i, st4) * f63;                              \
        float ex0 = q1.x * invs, ex1 = q1.y * invs;                          \
        float ex2 = q1.z * invs, ex3 = q1.w * invs;                          \
        STEP_BODY(NL, ex0, ex1, ex2, ex3, em1, ei1, 0);                      \
        LOADR(q1, st1, __builtin_amdgcn_readlane(tkv.y, (IT) + 1));          \
        STEP_BODY(NL, q2.x, q2.y, q2.z, q2.w, em2, ei2, 0);                  \
        LOADR(q2, st2, __builtin_amdgcn_readlane(tkv.z, (IT) + 1));          \
        STEP_BODY(NL, q3.x, q3.y, q3.z, q3.w, em3, ei3, 0);                  \
        LOADR(q3, st3, __builtin_amdgcn_readlane(tkv.w, (IT) + 1));          \
        STEP_BODY(NL, q4.x, q4.y, q4.z, q4.w, em4, ei4, 1);                  \
        int it2 = ((IT) + 2 < 64) ? ((IT) + 2) : 63;                         \
        LOADR(q4, st4, __builtin_amdgcn_readlane(tkv.x, it2));               \
        vsum = wave_sum_to63(part);          /* pending for next group */    \
    }

#define EPILOGUE(NL)                                                         \
    {                                                                        \
        float stot = readlane_f(vsum, 63);                                   \
        int sb = __float_as_int(stot) & 0x7f800000;                          \
        etot += (sb >> 23);                                                  \
        float invs = __int_as_float(0x7f000000 - sb);                        \
        float vinv63 = f63 * invs;                                           \
        float em1 = readlane_f(e2m, st1) * vinv63;                           \
        float ei1 = readlane_f(e2i, st1) * vinv63;                           \
        float em2 = readlane_f(e2m, st2) * f63;                              \
        float ei2 = readlane_f(e2i, st2) * f63;                              \
        float em3 = readlane_f(e2m, st3) * f63;                              \
        float ei3 = readlane_f(e2i, st3) * f63;                              \
        float ex0 = q1.x * invs, ex1 = q1.y * invs;                          \
        float ex2 = q1.z * invs, ex3 = q1.w * invs;                          \
        STEP_BODY(NL, ex0, ex1, ex2, ex3, em1, ei1, 0);                      \
        STEP_BODY(NL, q2.x, q2.y, q2.z, q2.w, em2, ei2, 0);                  \
        STEP_BODY(NL, q3.x, q3.y, q3.z, q3.w, em3, ei3, 1);                  \
    }

    if (fast) {
        for (int it = 0; it < 63; ++it) GROUP(1, it)
        EPILOGUE(1)
    } else {
        for (int it = 0; it < 63; ++it) GROUP(6, it)
        EPILOGUE(6)
    }
#undef GROUP
#undef EPILOGUE
#undef STEP_BODY
#undef LOADR

    float s = wave_sum_to63(part);
    if (lane == 63)
        out[b] = (float)(etot - 64 * 127) * 0.6931471805599453f + logf(s);
}

extern "C" void kernel_launch(void* const* d_in, const int* in_sizes, int n_in,
                              void* d_out, int out_size, void* d_ws, size_t ws_size,
                              hipStream_t stream) {
    const float* data  = (const float*)d_in[0];
    const float* z     = (const float*)d_in[1];
    const float* dec_W = (const float*)d_in[2];
    const float* dec_b = (const float*)d_in[3];
    const float* ins   = (const float*)d_in[4];
    const float* del   = (const float*)d_in[5];
    const float* invt  = (const float*)d_in[6];
    float* out = (float*)d_out;

    float* ws   = (float*)d_ws;
    float* ETg  = ws + OFF_ETG;
    float* E2g  = ws + OFF_E2G;
    int*   tok  = (int*)(ws + OFF_TOK);
    float* coef = ws + OFF_COEF;

    k_setup<<<1 + EMIS_BLKS + TOK_BLKS, 256, 0, stream>>>(z, dec_W, dec_b, invt,
                                                          data, ins, del, ETg, E2g,
                                                          tok, coef);
    k_fwd<<<BB, 64, 0, stream>>>(ETg, E2g, tok, coef, out);
}